// Round 5
// baseline (38.416 us; speedup 1.0000x reference)
//
#include <hip/hip_runtime.h>
#include <math.h>

#define NB   4
#define NS   1024
#define DIN  256
#define DOUT 64
#define NQ   128
#define NK   6
#define NROW (NB*NS)        // 4096
#define NF   (NQ*NK*2)      // 1536
#define ROWS 16
#define THR  1024
#define NBLK (NROW/ROWS)    // 256
#define MAGIC 0x1357A5A5u

typedef __attribute__((ext_vector_type(8))) short  short8;
typedef __attribute__((ext_vector_type(4))) short  short4v;
typedef __attribute__((ext_vector_type(4))) float  f32x4;

static __device__ __forceinline__ unsigned short f2bf(float x) {
    unsigned int u = __float_as_uint(x);
    u = (u + 0x7fffu + ((u >> 16) & 1u)) >> 16;   // RNE
    return (unsigned short)u;
}
static __device__ __forceinline__ float bf2f(unsigned short h) {
    return __uint_as_float(((unsigned int)h) << 16);
}

// ---------------------------------------------------------------------------
// Single kernel, 256 blocks x 1024 threads (16 waves), 64 KiB LDS.
//  phase 0: tid<192 computes this block's 192-entry W2T slice -> global ws
//           (overlapped with the X0 global load issued first)
//  phase 1: X0[16][256] -> LDS as hi/lo bf16 (row-xor swizzle)
//  release: syncthreads; tid0: threadfence + flags[bid]=MAGIC
//  phase 2: angle[16][128] = X0 x Wc^T via 3-pass hi/lo MFMA
//           (Wc hi/lo split computed on the fly from fp32 Wcw)
//  phase 3: all 16 waves: 2 angles/lane -> sincos -> 12 bf16 features -> LDS
//  acquire: tid<256 spin on flags (relaxed, idempotent magic - no reset
//           needed across graph replays since W2T values are call-invariant);
//           threadfence; barrier
//  phase 4: V[16][64] = F[16][1536] x W2T^T  (waves: dt = w&3, kq = w>>2)
// ---------------------------------------------------------------------------
__global__ __launch_bounds__(THR) void k_main(const float* __restrict__ X0,
                                              const float* __restrict__ tvec,
                                              const float* __restrict__ Wcw,
                                              const float* __restrict__ Wcb,
                                              const float* __restrict__ wq,
                                              const float* __restrict__ A,
                                              const float* __restrict__ Bp,
                                              unsigned short* __restrict__ W2T,
                                              unsigned int* __restrict__ flags,
                                              float* __restrict__ V) {
    __shared__ char smem[65536];
    const int row0 = blockIdx.x * ROWS;
    const int tid  = threadIdx.x;
    const int lane = tid & 63;
    const int w    = tid >> 6;

    // ---- issue X0 load first (latency hides under phase 0) ---------------
    const int r  = w;                             // wave-uniform row 0..15
    const int kk = lane * 4;
    float4 x = *(const float4*)(X0 + (size_t)(row0 + r) * DIN + kk);

    // ---- phase 0: this block's W2T slice ----------------------------------
    if (tid < 192) {
        int e   = blockIdx.x * 192 + tid;         // covers DOUT*NQ*NK = 49152
        int d   = e / (NQ * NK);
        int rem = e - d * (NQ * NK);
        int q   = rem / NK;
        int k   = rem - q * NK;
        float a = A[e], bp = Bp[e];
        float sb, cb;
        __sincosf(bp, &sb, &cb);
        W2T[(size_t)d * NF + (k * 2 + 0) * NQ + q] = f2bf(a * cb);
        W2T[(size_t)d * NF + (k * 2 + 1) * NQ + q] = f2bf(a * sb);
    }

    // ---- phase 1: X0 -> LDS hi/lo bf16 (row-xor) ---------------------------
    {
        unsigned short h0 = f2bf(x.x), h1 = f2bf(x.y), h2 = f2bf(x.z), h3 = f2bf(x.w);
        short4v hv = {(short)h0, (short)h1, (short)h2, (short)h3};
        short4v lv = {(short)f2bf(x.x - bf2f(h0)), (short)f2bf(x.y - bf2f(h1)),
                      (short)f2bf(x.z - bf2f(h2)), (short)f2bf(x.w - bf2f(h3))};
        int off = (r * 512 + kk * 2) ^ ((r & 7) << 4);
        *(short4v*)(smem + off)        = hv;
        *(short4v*)(smem + 8192 + off) = lv;
    }
    __syncthreads();                              // W2T slice + X stage done

    // ---- release: publish this block's W2T slice ---------------------------
    if (tid == 0) {
        __threadfence();                          // agent fence: flush XCD L2
        __hip_atomic_store(&flags[blockIdx.x], MAGIC,
                           __ATOMIC_RELAXED, __HIP_MEMORY_SCOPE_AGENT);
    }

    // ---- phase 2: angle MFMA, on-the-fly hi/lo split of Wcw ---------------
    const int qt  = w & 7;
    const int kh  = w >> 3;
    const int col = lane & 15;
    const int kg  = lane >> 4;
    const int q   = qt * 16 + col;
    const int asw = (col & 7) << 4;

    f32x4 acc = {0.f, 0.f, 0.f, 0.f};
    {
        const float* wrow = Wcw + (size_t)q * DIN + kh * 128 + kg * 8;
        #pragma unroll
        for (int s = 0; s < 4; ++s) {
            int k    = kh * 128 + s * 32 + kg * 8;
            int aoff = (col * 512 + k * 2) ^ asw;
            short8 ah = *(const short8*)(smem + aoff);
            short8 al = *(const short8*)(smem + 8192 + aoff);
            float4 w0 = *(const float4*)(wrow + s * 32);
            float4 w1 = *(const float4*)(wrow + s * 32 + 4);
            float wf[8] = {w0.x, w0.y, w0.z, w0.w, w1.x, w1.y, w1.z, w1.w};
            short8 bh, bl;
            #pragma unroll
            for (int j = 0; j < 8; ++j) {
                unsigned short h = f2bf(wf[j]);
                bh[j] = (short)h;
                bl[j] = (short)f2bf(wf[j] - bf2f(h));
            }
            acc = __builtin_amdgcn_mfma_f32_16x16x32_bf16(ah, bh, acc, 0, 0, 0);
            acc = __builtin_amdgcn_mfma_f32_16x16x32_bf16(ah, bl, acc, 0, 0, 0);
            acc = __builtin_amdgcn_mfma_f32_16x16x32_bf16(al, bh, acc, 0, 0, 0);
        }
    }

    // ---- phase 3: both K-halves exchange partials, each does 2 angles ------
    f32x4* R2A = (f32x4*)(smem + 49152);          // [2][8][64] f32x4 = 16 KiB
    R2A[(kh * 8 + qt) * 64 + lane] = acc;
    __syncthreads();
    {
        f32x4 other = R2A[((1 - kh) * 8 + qt) * 64 + lane];
        const int   b    = row0 >> 10;
        const float bias = Wcb[q] + wq[q] * tvec[b];
        #pragma unroll
        for (int jj = 0; jj < 2; ++jj) {
            int   j  = kh * 2 + jj;               // D: row = kg*4+j, col = q
            float a  = acc[j] + other[j] + bias;
            int   rr = kg * 4 + j;
            int   sw = (rr & 7) << 4;
            char* base = smem + rr * (NF * 2);
            float s1, c1;
            __sincosf(a, &s1, &c1);
            float sk = s1, ck = c1;
            *(unsigned short*)(base + (((0 * NQ + q) * 2) ^ sw)) = f2bf(sk);
            *(unsigned short*)(base + (((1 * NQ + q) * 2) ^ sw)) = f2bf(ck);
            #pragma unroll
            for (int k = 1; k < NK; ++k) {
                float sn = sk * c1 + ck * s1;     // sin((k+1)a)
                float cn = ck * c1 - sk * s1;     // cos((k+1)a)
                *(unsigned short*)(base + ((((k * 2 + 0) * NQ + q) * 2) ^ sw)) = f2bf(sn);
                *(unsigned short*)(base + ((((k * 2 + 1) * NQ + q) * 2) ^ sw)) = f2bf(cn);
                sk = sn; ck = cn;
            }
        }
    }
    __syncthreads();                              // F complete

    // ---- acquire: wait for all 256 W2T slices ------------------------------
    if (tid < NBLK) {
        while (__hip_atomic_load(&flags[tid], __ATOMIC_RELAXED,
                                 __HIP_MEMORY_SCOPE_AGENT) != MAGIC)
            __builtin_amdgcn_s_sleep(2);
        __threadfence();                          // invalidate stale L1/L2
    }
    __syncthreads();

    // ---- phase 4: V = F x W2T^T --------------------------------------------
    const int dt = w & 3;
    const int kq = w >> 2;
    f32x4 c2 = {0.f, 0.f, 0.f, 0.f};
    const unsigned short* wb = W2T + (size_t)(dt * 16 + col) * NF + kg * 8;
    #pragma unroll 4
    for (int kt = 0; kt < 12; ++kt) {
        int k0   = kq * 384 + kt * 32;
        int aoff = (col * (NF * 2) + (k0 + kg * 8) * 2) ^ asw;
        short8 af = *(const short8*)(smem + aoff);
        short8 bf = *(const short8*)(wb + k0);
        c2 = __builtin_amdgcn_mfma_f32_16x16x32_bf16(af, bf, c2, 0, 0, 0);
    }
    f32x4* R4 = (f32x4*)(smem + 49152);           // reuse reduce region
    if (kq != 0) R4[(kq * 4 + dt) * 64 + lane] = c2;
    __syncthreads();
    if (kq == 0) {
        c2 += R4[(1 * 4 + dt) * 64 + lane];
        c2 += R4[(2 * 4 + dt) * 64 + lane];
        c2 += R4[(3 * 4 + dt) * 64 + lane];
        const int d = dt * 16 + col;
        #pragma unroll
        for (int j = 0; j < 4; ++j)
            V[(size_t)(row0 + kg * 4 + j) * DOUT + d] = c2[j];
    }
}

// ---------------------------------------------------------------------------
extern "C" void kernel_launch(void* const* d_in, const int* in_sizes, int n_in,
                              void* d_out, int out_size, void* d_ws, size_t ws_size,
                              hipStream_t stream) {
    const float* X0   = (const float*)d_in[0];   // [4,1024,256]
    const float* tvec = (const float*)d_in[1];   // [4,1]
    const float* Wcw  = (const float*)d_in[2];   // [128,256]
    const float* Wcb  = (const float*)d_in[3];   // [128]
    const float* wq   = (const float*)d_in[4];   // [128]
    const float* A    = (const float*)d_in[5];   // [64,128,6]
    const float* Bp   = (const float*)d_in[6];   // [64,128,6]
    float*       V    = (float*)d_out;           // [4,1024,64]

    unsigned short* W2T   = (unsigned short*)d_ws;                 // 196608 B
    unsigned int*   flags = (unsigned int*)((char*)d_ws + 196608); // 1024 B

    k_main<<<NBLK, THR, 0, stream>>>(X0, tvec, Wcw, Wcb, wq, A, Bp,
                                     W2T, flags, V);
}

// Round 6
// 22.371 us; speedup vs baseline: 1.7172x; 1.7172x over previous
//
#include <hip/hip_runtime.h>
#include <math.h>

#define NB   4
#define NS   1024
#define DIN  256
#define DOUT 64
#define NQ   128
#define NK   6
#define NROW (NB*NS)        // 4096
#define NF   (NQ*NK*2)      // 1536
#define ROWS 16
#define THR  1024
#define NBLK (NROW/ROWS)    // 256

typedef __attribute__((ext_vector_type(8))) short  short8;
typedef __attribute__((ext_vector_type(4))) short  short4v;
typedef __attribute__((ext_vector_type(4))) float  f32x4;

static __device__ __forceinline__ unsigned short f2bf(float x) {
    unsigned int u = __float_as_uint(x);
    u = (u + 0x7fffu + ((u >> 16) & 1u)) >> 16;   // RNE
    return (unsigned short)u;
}
static __device__ __forceinline__ float bf2f(unsigned short h) {
    return __uint_as_float(((unsigned int)h) << 16);
}

// ---------------------------------------------------------------------------
// K0: W2T[d][f] bf16, f=(k*2+c)*NQ+q  (c=0: A*cos(Bp), pairs sin((k+1)a);
//                                      c=1: A*sin(Bp), pairs cos((k+1)a))
// ---------------------------------------------------------------------------
__global__ __launch_bounds__(256) void k0_prep(const float* __restrict__ A,
                                               const float* __restrict__ Bp,
                                               unsigned short* __restrict__ W2T) {
    int idx = blockIdx.x * 256 + threadIdx.x;     // [0, DOUT*NQ*NK)
    if (idx >= DOUT * NQ * NK) return;
    int d   = idx / (NQ * NK);
    int rem = idx - d * (NQ * NK);
    int q   = rem / NK;
    int k   = rem - q * NK;
    float a = A[idx], bp = Bp[idx];
    float sb, cb;
    __sincosf(bp, &sb, &cb);
    W2T[(size_t)d * NF + (k * 2 + 0) * NQ + q] = f2bf(a * cb);
    W2T[(size_t)d * NF + (k * 2 + 1) * NQ + q] = f2bf(a * sb);
}

// ---------------------------------------------------------------------------
// k_main: 256 blocks x 1024 thr (16 waves), 64 KiB LDS.
//  entry:   prefetch 12 short8 W2T B-fragments -> 48 VGPRs (hides L2 read
//           under phases 1-3); issue X0 float4 load
//  phase 1: X0[16][256] -> LDS hi/lo bf16 (row-xor swizzle)
//  phase 2: angle[16][128] = X0 x Wc^T, 3-pass hi/lo MFMA, Wc split on the fly
//  phase 3: all 16 waves: 2 angles/lane -> sincos -> 12 bf16 features -> LDS
//  phase 4: V[16][64] = F[16][1536] x W2T^T from prefetched B-frags
//           (waves: dt = w&3, kq = w>>2; partials reduced via LDS)
// ---------------------------------------------------------------------------
__global__ __launch_bounds__(THR) void k_main(const float* __restrict__ X0,
                                              const float* __restrict__ tvec,
                                              const float* __restrict__ Wcw,
                                              const float* __restrict__ Wcb,
                                              const float* __restrict__ wq,
                                              const unsigned short* __restrict__ W2T,
                                              float* __restrict__ V) {
    __shared__ char smem[65536];
    const int row0 = blockIdx.x * ROWS;
    const int tid  = threadIdx.x;
    const int lane = tid & 63;
    const int w    = tid >> 6;
    const int col  = lane & 15;
    const int kg   = lane >> 4;
    const int asw  = (col & 7) << 4;

    // ---- entry prefetches --------------------------------------------------
    const int dt = w & 3;
    const int kq = w >> 2;
    short8 bpre[12];
    {
        const unsigned short* wb =
            W2T + (size_t)(dt * 16 + col) * NF + kq * 384 + kg * 8;
        #pragma unroll
        for (int kt = 0; kt < 12; ++kt)
            bpre[kt] = *(const short8*)(wb + kt * 32);
    }
    const int r  = w;                             // wave-uniform row 0..15
    const int kk = lane * 4;
    float4 x = *(const float4*)(X0 + (size_t)(row0 + r) * DIN + kk);

    // ---- phase 1: X0 -> LDS hi/lo bf16 (row-xor) ---------------------------
    {
        unsigned short h0 = f2bf(x.x), h1 = f2bf(x.y), h2 = f2bf(x.z), h3 = f2bf(x.w);
        short4v hv = {(short)h0, (short)h1, (short)h2, (short)h3};
        short4v lv = {(short)f2bf(x.x - bf2f(h0)), (short)f2bf(x.y - bf2f(h1)),
                      (short)f2bf(x.z - bf2f(h2)), (short)f2bf(x.w - bf2f(h3))};
        int off = (r * 512 + kk * 2) ^ ((r & 7) << 4);
        *(short4v*)(smem + off)        = hv;
        *(short4v*)(smem + 8192 + off) = lv;
    }
    __syncthreads();

    // ---- phase 2: angle MFMA, on-the-fly hi/lo split of Wcw ----------------
    const int qt = w & 7;
    const int kh = w >> 3;
    const int q  = qt * 16 + col;

    f32x4 acc = {0.f, 0.f, 0.f, 0.f};
    {
        const float* wrow = Wcw + (size_t)q * DIN + kh * 128 + kg * 8;
        #pragma unroll
        for (int s = 0; s < 4; ++s) {
            int k    = kh * 128 + s * 32 + kg * 8;
            int aoff = (col * 512 + k * 2) ^ asw;
            short8 ah = *(const short8*)(smem + aoff);
            short8 al = *(const short8*)(smem + 8192 + aoff);
            float4 w0 = *(const float4*)(wrow + s * 32);
            float4 w1 = *(const float4*)(wrow + s * 32 + 4);
            float wf[8] = {w0.x, w0.y, w0.z, w0.w, w1.x, w1.y, w1.z, w1.w};
            short8 bh, bl;
            #pragma unroll
            for (int j = 0; j < 8; ++j) {
                unsigned short h = f2bf(wf[j]);
                bh[j] = (short)h;
                bl[j] = (short)f2bf(wf[j] - bf2f(h));
            }
            acc = __builtin_amdgcn_mfma_f32_16x16x32_bf16(ah, bh, acc, 0, 0, 0);
            acc = __builtin_amdgcn_mfma_f32_16x16x32_bf16(ah, bl, acc, 0, 0, 0);
            acc = __builtin_amdgcn_mfma_f32_16x16x32_bf16(al, bh, acc, 0, 0, 0);
        }
    }

    // ---- phase 3: exchange K-half partials; 2 angles per lane --------------
    f32x4* R2A = (f32x4*)(smem + 49152);          // [2][8][64] f32x4 = 16 KiB
    R2A[(kh * 8 + qt) * 64 + lane] = acc;
    __syncthreads();
    {
        f32x4 other = R2A[((1 - kh) * 8 + qt) * 64 + lane];
        const int   b    = row0 >> 10;
        const float bias = Wcb[q] + wq[q] * tvec[b];
        #pragma unroll
        for (int jj = 0; jj < 2; ++jj) {
            int   j  = kh * 2 + jj;               // D: row = kg*4+j, col = q
            float a  = acc[j] + other[j] + bias;
            int   rr = kg * 4 + j;
            int   sw = (rr & 7) << 4;
            char* base = smem + rr * (NF * 2);
            float s1, c1;
            __sincosf(a, &s1, &c1);
            float sk = s1, ck = c1;
            *(unsigned short*)(base + (((0 * NQ + q) * 2) ^ sw)) = f2bf(sk);
            *(unsigned short*)(base + (((1 * NQ + q) * 2) ^ sw)) = f2bf(ck);
            #pragma unroll
            for (int k = 1; k < NK; ++k) {
                float sn = sk * c1 + ck * s1;     // sin((k+1)a)
                float cn = ck * c1 - sk * s1;     // cos((k+1)a)
                *(unsigned short*)(base + ((((k * 2 + 0) * NQ + q) * 2) ^ sw)) = f2bf(sn);
                *(unsigned short*)(base + ((((k * 2 + 1) * NQ + q) * 2) ^ sw)) = f2bf(cn);
                sk = sn; ck = cn;
            }
        }
    }
    __syncthreads();                              // F complete

    // ---- phase 4: V = F x W2T^T (B-frags already in registers) -------------
    f32x4 c2 = {0.f, 0.f, 0.f, 0.f};
    #pragma unroll
    for (int kt = 0; kt < 12; ++kt) {
        int k0   = kq * 384 + kt * 32;
        int aoff = (col * (NF * 2) + (k0 + kg * 8) * 2) ^ asw;
        short8 af = *(const short8*)(smem + aoff);
        c2 = __builtin_amdgcn_mfma_f32_16x16x32_bf16(af, bpre[kt], c2, 0, 0, 0);
    }
    f32x4* R4 = (f32x4*)(smem + 49152);           // reuse reduce region
    if (kq != 0) R4[(kq * 4 + dt) * 64 + lane] = c2;
    __syncthreads();
    if (kq == 0) {
        c2 += R4[(1 * 4 + dt) * 64 + lane];
        c2 += R4[(2 * 4 + dt) * 64 + lane];
        c2 += R4[(3 * 4 + dt) * 64 + lane];
        const int d = dt * 16 + col;
        #pragma unroll
        for (int j = 0; j < 4; ++j)
            V[(size_t)(row0 + kg * 4 + j) * DOUT + d] = c2[j];
    }
}

// ---------------------------------------------------------------------------
extern "C" void kernel_launch(void* const* d_in, const int* in_sizes, int n_in,
                              void* d_out, int out_size, void* d_ws, size_t ws_size,
                              hipStream_t stream) {
    const float* X0   = (const float*)d_in[0];   // [4,1024,256]
    const float* tvec = (const float*)d_in[1];   // [4,1]
    const float* Wcw  = (const float*)d_in[2];   // [128,256]
    const float* Wcb  = (const float*)d_in[3];   // [128]
    const float* wq   = (const float*)d_in[4];   // [128]
    const float* A    = (const float*)d_in[5];   // [64,128,6]
    const float* Bp   = (const float*)d_in[6];   // [64,128,6]
    float*       V    = (float*)d_out;           // [4,1024,64]

    unsigned short* W2T = (unsigned short*)d_ws; // 196608 B

    k0_prep<<<(DOUT * NQ * NK + 255) / 256, 256, 0, stream>>>(A, Bp, W2T);
    k_main <<<NBLK, THR, 0, stream>>>(X0, tvec, Wcw, Wcb, wq, W2T, V);
}

// Round 7
// 22.359 us; speedup vs baseline: 1.7181x; 1.0005x over previous
//
#include <hip/hip_runtime.h>
#include <math.h>

#define NB   4
#define NS   1024
#define DIN  256
#define DOUT 64
#define NQ   128
#define NK   6
#define NROW (NB*NS)        // 4096
#define NF   (NQ*NK*2)      // 1536
#define ROWS 16
#define THR  1024
#define NBLK (NROW/ROWS)    // 256

// ws layout (unsigned short elements)
#define W2T_OFF 0                        // [DOUT][NF]   196608 B
#define WCH_OFF (DOUT*NF)                // [NQ][DIN]    65536 B
#define WCL_OFF (DOUT*NF + NQ*DIN)       // [NQ][DIN]    65536 B

typedef __attribute__((ext_vector_type(8))) short  short8;
typedef __attribute__((ext_vector_type(4))) short  short4v;
typedef __attribute__((ext_vector_type(4))) float  f32x4;

static __device__ __forceinline__ unsigned short f2bf(float x) {
    unsigned int u = __float_as_uint(x);
    u = (u + 0x7fffu + ((u >> 16) & 1u)) >> 16;   // RNE
    return (unsigned short)u;
}
static __device__ __forceinline__ float bf2f(unsigned short h) {
    return __uint_as_float(((unsigned int)h) << 16);
}

// ---------------------------------------------------------------------------
// K0: (a) W2T[d][f] bf16, f=(k*2+c)*NQ+q (c=0: A*cosB -> sin((k+1)a) term;
//                                          c=1: A*sinB -> cos((k+1)a) term)
//     (b) hi/lo bf16 split of Wcw (x ~= hi+lo, ~16-bit effective mantissa)
// 320 blocks x 256 thr; launch-overhead bound.
// ---------------------------------------------------------------------------
__global__ __launch_bounds__(256) void k0_prep(const float* __restrict__ A,
                                               const float* __restrict__ Bp,
                                               const float* __restrict__ Wcw,
                                               unsigned short* __restrict__ ws) {
    int idx = blockIdx.x * 256 + threadIdx.x;
    if (idx < DOUT * NQ * NK) {
        int d   = idx / (NQ * NK);
        int rem = idx - d * (NQ * NK);
        int q   = rem / NK;
        int k   = rem - q * NK;
        float a = A[idx], bp = Bp[idx];
        float sb, cb;
        __sincosf(bp, &sb, &cb);
        ws[W2T_OFF + (size_t)d * NF + (k * 2 + 0) * NQ + q] = f2bf(a * cb);
        ws[W2T_OFF + (size_t)d * NF + (k * 2 + 1) * NQ + q] = f2bf(a * sb);
    } else {
        int j = idx - DOUT * NQ * NK;
        if (j < NQ * DIN) {
            float x = Wcw[j];
            unsigned short h = f2bf(x);
            ws[WCH_OFF + j] = h;
            ws[WCL_OFF + j] = f2bf(x - bf2f(h));
        }
    }
}

// ---------------------------------------------------------------------------
// k_main: 256 blocks x 1024 thr (16 waves), 64 KiB LDS.
//  entry:   issue X0 float4 load; prefetch 12 short8 W2T B-frags -> 48 VGPRs
//  phase 1: X0[16][256] -> LDS hi/lo bf16 (row-xor swizzle)
//  phase 2: angle[16][128] = X0 x Wc^T, 3-pass hi/lo MFMA, B-frags from ws
//  phase 3: all 16 waves: 2 angles/lane -> sincos -> 12 bf16 features -> LDS
//  phase 4: V[16][64] = F[16][1536] x W2T^T from prefetched B-frags
// ---------------------------------------------------------------------------
__global__ __launch_bounds__(THR) void k_main(const float* __restrict__ X0,
                                              const float* __restrict__ tvec,
                                              const float* __restrict__ Wcb,
                                              const float* __restrict__ wq,
                                              const unsigned short* __restrict__ ws,
                                              float* __restrict__ V) {
    __shared__ char smem[65536];
    const int row0 = blockIdx.x * ROWS;
    const int tid  = threadIdx.x;
    const int lane = tid & 63;
    const int w    = tid >> 6;
    const int col  = lane & 15;
    const int kg   = lane >> 4;
    const int asw  = (col & 7) << 4;

    // ---- entry: X0 load + phase-4 B-frag prefetch --------------------------
    const int r  = w;                             // wave-uniform row 0..15
    const int kk = lane * 4;
    float4 x = *(const float4*)(X0 + (size_t)(row0 + r) * DIN + kk);

    const int dt = w & 3;
    const int kq = w >> 2;
    short8 bpre[12];
    {
        const unsigned short* wb =
            ws + W2T_OFF + (size_t)(dt * 16 + col) * NF + kq * 384 + kg * 8;
        #pragma unroll
        for (int kt = 0; kt < 12; ++kt)
            bpre[kt] = *(const short8*)(wb + kt * 32);
    }

    // ---- phase 1: X0 -> LDS hi/lo bf16 (row-xor) ---------------------------
    {
        unsigned short h0 = f2bf(x.x), h1 = f2bf(x.y), h2 = f2bf(x.z), h3 = f2bf(x.w);
        short4v hv = {(short)h0, (short)h1, (short)h2, (short)h3};
        short4v lv = {(short)f2bf(x.x - bf2f(h0)), (short)f2bf(x.y - bf2f(h1)),
                      (short)f2bf(x.z - bf2f(h2)), (short)f2bf(x.w - bf2f(h3))};
        int off = (r * 512 + kk * 2) ^ ((r & 7) << 4);
        *(short4v*)(smem + off)        = hv;
        *(short4v*)(smem + 8192 + off) = lv;
    }
    __syncthreads();

    // ---- phase 2: angle MFMA, precomputed hi/lo Wc from ws -----------------
    const int qt = w & 7;
    const int kh = w >> 3;
    const int q  = qt * 16 + col;

    f32x4 acc = {0.f, 0.f, 0.f, 0.f};
    {
        const unsigned short* bhp = ws + WCH_OFF + (size_t)q * DIN + kh * 128 + kg * 8;
        const unsigned short* blp = ws + WCL_OFF + (size_t)q * DIN + kh * 128 + kg * 8;
        #pragma unroll
        for (int s = 0; s < 4; ++s) {
            int k    = kh * 128 + s * 32 + kg * 8;
            int aoff = (col * 512 + k * 2) ^ asw;
            short8 ah = *(const short8*)(smem + aoff);
            short8 al = *(const short8*)(smem + 8192 + aoff);
            short8 bh = *(const short8*)(bhp + s * 32);
            short8 bl = *(const short8*)(blp + s * 32);
            acc = __builtin_amdgcn_mfma_f32_16x16x32_bf16(ah, bh, acc, 0, 0, 0);
            acc = __builtin_amdgcn_mfma_f32_16x16x32_bf16(ah, bl, acc, 0, 0, 0);
            acc = __builtin_amdgcn_mfma_f32_16x16x32_bf16(al, bh, acc, 0, 0, 0);
        }
    }

    // ---- phase 3: exchange K-half partials; 2 angles per lane --------------
    f32x4* R2A = (f32x4*)(smem + 49152);          // [2][8][64] f32x4 = 16 KiB
    R2A[(kh * 8 + qt) * 64 + lane] = acc;
    __syncthreads();
    {
        f32x4 other = R2A[((1 - kh) * 8 + qt) * 64 + lane];
        const int   b    = row0 >> 10;
        const float bias = Wcb[q] + wq[q] * tvec[b];
        #pragma unroll
        for (int jj = 0; jj < 2; ++jj) {
            int   j  = kh * 2 + jj;               // D: row = kg*4+j, col = q
            float a  = acc[j] + other[j] + bias;
            int   rr = kg * 4 + j;
            int   sw = (rr & 7) << 4;
            char* base = smem + rr * (NF * 2);
            float s1, c1;
            __sincosf(a, &s1, &c1);
            float sk = s1, ck = c1;
            *(unsigned short*)(base + (((0 * NQ + q) * 2) ^ sw)) = f2bf(sk);
            *(unsigned short*)(base + (((1 * NQ + q) * 2) ^ sw)) = f2bf(ck);
            #pragma unroll
            for (int k = 1; k < NK; ++k) {
                float sn = sk * c1 + ck * s1;     // sin((k+1)a)
                float cn = ck * c1 - sk * s1;     // cos((k+1)a)
                *(unsigned short*)(base + ((((k * 2 + 0) * NQ + q) * 2) ^ sw)) = f2bf(sn);
                *(unsigned short*)(base + ((((k * 2 + 1) * NQ + q) * 2) ^ sw)) = f2bf(cn);
                sk = sn; ck = cn;
            }
        }
    }
    __syncthreads();                              // F complete

    // ---- phase 4: V = F x W2T^T (B-frags in registers) ---------------------
    f32x4 c2 = {0.f, 0.f, 0.f, 0.f};
    #pragma unroll
    for (int kt = 0; kt < 12; ++kt) {
        int k0   = kq * 384 + kt * 32;
        int aoff = (col * (NF * 2) + (k0 + kg * 8) * 2) ^ asw;
        short8 af = *(const short8*)(smem + aoff);
        c2 = __builtin_amdgcn_mfma_f32_16x16x32_bf16(af, bpre[kt], c2, 0, 0, 0);
    }
    f32x4* R4 = (f32x4*)(smem + 49152);           // reuse reduce region
    if (kq != 0) R4[(kq * 4 + dt) * 64 + lane] = c2;
    __syncthreads();
    if (kq == 0) {
        c2 += R4[(1 * 4 + dt) * 64 + lane];
        c2 += R4[(2 * 4 + dt) * 64 + lane];
        c2 += R4[(3 * 4 + dt) * 64 + lane];
        const int d = dt * 16 + col;
        #pragma unroll
        for (int j = 0; j < 4; ++j)
            V[(size_t)(row0 + kg * 4 + j) * DOUT + d] = c2[j];
    }
}

// ---------------------------------------------------------------------------
extern "C" void kernel_launch(void* const* d_in, const int* in_sizes, int n_in,
                              void* d_out, int out_size, void* d_ws, size_t ws_size,
                              hipStream_t stream) {
    const float* X0   = (const float*)d_in[0];   // [4,1024,256]
    const float* tvec = (const float*)d_in[1];   // [4,1]
    const float* Wcw  = (const float*)d_in[2];   // [128,256]
    const float* Wcb  = (const float*)d_in[3];   // [128]
    const float* wq   = (const float*)d_in[4];   // [128]
    const float* A    = (const float*)d_in[5];   // [64,128,6]
    const float* Bp   = (const float*)d_in[6];   // [64,128,6]
    float*       V    = (float*)d_out;           // [4,1024,64]

    unsigned short* ws = (unsigned short*)d_ws;  // 327680 B

    k0_prep<<<(DOUT * NQ * NK + NQ * DIN + 255) / 256, 256, 0, stream>>>(A, Bp, Wcw, ws);
    k_main <<<NBLK, THR, 0, stream>>>(X0, tvec, Wcb, wq, ws, V);
}